// Round 1
// baseline (1553.774 us; speedup 1.0000x reference)
//
#include <hip/hip_runtime.h>

#define D 64

__global__ void count_kernel(const int* __restrict__ dst, float* __restrict__ cnt, int E) {
    int i = blockIdx.x * blockDim.x + threadIdx.x;
    int stride = gridDim.x * blockDim.x;
    for (; i < E; i += stride)
        atomicAdd(&cnt[dst[i]], 1.0f);
}

// 16 lanes per edge: each lane gathers a float4 of the source row and
// atomically accumulates into the destination row.
__global__ void scatter_kernel(const float* __restrict__ xin,
                               const int* __restrict__ src,
                               const int* __restrict__ dst,
                               float* __restrict__ ssum, int E) {
    int gid = blockIdx.x * blockDim.x + threadIdx.x;
    int lane = gid & 15;
    int e = gid >> 4;
    int estride = (gridDim.x * blockDim.x) >> 4;
    for (; e < E; e += estride) {
        int s = src[e];
        int t = dst[e];
        const float4 v = *reinterpret_cast<const float4*>(xin + (size_t)s * D + (size_t)lane * 4);
        float* o = ssum + (size_t)t * D + (size_t)lane * 4;
        atomicAdd(o + 0, v.x);
        atomicAdd(o + 1, v.y);
        atomicAdd(o + 2, v.z);
        atomicAdd(o + 3, v.w);
    }
}

// out[n][d] = (ssum[n]/max(cnt,1)) . Wl[d,:] + xin[n] . Wr[d,:] + b[d]
// Block = 256 threads = 4 nodes x 64 dims. W staged transposed in LDS (+1 pad).
__global__ void layer_kernel(const float* __restrict__ xin,
                             const float* __restrict__ ssum,
                             const float* __restrict__ cnt,
                             const float* __restrict__ Wl,
                             const float* __restrict__ Wr,
                             const float* __restrict__ b,
                             float* __restrict__ out,
                             int do_relu) {
    __shared__ float wlT[D][D + 1];
    __shared__ float wrT[D][D + 1];
    __shared__ float xrow[4][D];
    __shared__ float mrow[4][D];
    int tid = threadIdx.x;
    for (int j = tid; j < D * D; j += 256) {
        int dd = j >> 6, k = j & 63;
        wlT[k][dd] = Wl[j];   // write addr k*65+dd: consecutive k -> bank stride 1, no conflict
        wrT[k][dd] = Wr[j];
    }
    int local = tid >> 6;
    int d = tid & 63;
    int node = blockIdx.x * 4 + local;   // N = 50000 divisible by 4, grid exact
    float c = cnt[node];
    float rinv = 1.0f / fmaxf(c, 1.0f);
    xrow[local][d] = xin[(size_t)node * D + d];
    mrow[local][d] = ssum[(size_t)node * D + d] * rinv;
    __syncthreads();
    float acc = b[d];
#pragma unroll
    for (int k = 0; k < D; ++k) {
        acc = fmaf(mrow[local][k], wlT[k][d], acc);  // mrow: broadcast (free); wlT: d-consecutive (free)
        acc = fmaf(xrow[local][k], wrT[k][d], acc);
    }
    if (do_relu) acc = fmaxf(acc, 0.0f);
    out[(size_t)node * D + d] = acc;
}

extern "C" void kernel_launch(void* const* d_in, const int* in_sizes, int n_in,
                              void* d_out, int out_size, void* d_ws, size_t ws_size,
                              hipStream_t stream) {
    const float* x   = (const float*)d_in[0];
    const int*   ei  = (const int*)d_in[1];
    const float* Wl1 = (const float*)d_in[2];
    const float* Wr1 = (const float*)d_in[3];
    const float* b1  = (const float*)d_in[4];
    const float* Wl2 = (const float*)d_in[5];
    const float* Wr2 = (const float*)d_in[6];
    const float* b2  = (const float*)d_in[7];

    int N_ = in_sizes[0] / D;   // 50000
    int E_ = in_sizes[1] / 2;   // 800000
    const int* src = ei;
    const int* dst = ei + E_;

    float* cnt  = (float*)d_ws;                 // [N]
    float* ssum = cnt + N_;                     // [N, D]
    float* h    = ssum + (size_t)N_ * D;        // [N, D]
    float* outp = (float*)d_out;

    // ws is poisoned 0xAA before every timed call — zero the accumulators.
    hipMemsetAsync(cnt, 0, ((size_t)N_ + (size_t)N_ * D) * sizeof(float), stream);

    count_kernel<<<2048, 256, 0, stream>>>(dst, cnt, E_);

    // Layer 1
    scatter_kernel<<<2048, 256, 0, stream>>>(x, src, dst, ssum, E_);
    layer_kernel<<<N_ / 4, 256, 0, stream>>>(x, ssum, cnt, Wl1, Wr1, b1, h, 1);

    // Layer 2
    hipMemsetAsync(ssum, 0, (size_t)N_ * D * sizeof(float), stream);
    scatter_kernel<<<2048, 256, 0, stream>>>(h, src, dst, ssum, E_);
    layer_kernel<<<N_ / 4, 256, 0, stream>>>(h, ssum, cnt, Wl2, Wr2, b2, outp, 0);
}

// Round 2
// 333.087 us; speedup vs baseline: 4.6648x; 4.6648x over previous
//
#include <hip/hip_runtime.h>

#define D 64
#define SCAN_BLOCK 256

__global__ void counti_kernel(const int* __restrict__ dst, int* __restrict__ cnti, int E) {
    int i = blockIdx.x * blockDim.x + threadIdx.x;
    int stride = gridDim.x * blockDim.x;
    for (; i < E; i += stride)
        atomicAdd(&cnti[dst[i]], 1);
}

// Block-wise inclusive scan (Hillis-Steele) -> exclusive per-element + block sums
__global__ void scan1_kernel(const int* __restrict__ cnti, int* __restrict__ excl,
                             int* __restrict__ bsum, int N) {
    __shared__ int tmp[SCAN_BLOCK];
    int gid = blockIdx.x * SCAN_BLOCK + threadIdx.x;
    int v = (gid < N) ? cnti[gid] : 0;
    tmp[threadIdx.x] = v;
    __syncthreads();
    for (int ofs = 1; ofs < SCAN_BLOCK; ofs <<= 1) {
        int t = (threadIdx.x >= ofs) ? tmp[threadIdx.x - ofs] : 0;
        __syncthreads();
        tmp[threadIdx.x] += t;
        __syncthreads();
    }
    if (gid < N) excl[gid] = tmp[threadIdx.x] - v;
    if (threadIdx.x == SCAN_BLOCK - 1) bsum[blockIdx.x] = tmp[SCAN_BLOCK - 1];
}

// Exclusive scan of block sums (numBlocks <= 256, single workgroup)
__global__ void scan2_kernel(int* __restrict__ bsum, int* __restrict__ bofs, int nb) {
    __shared__ int tmp[SCAN_BLOCK];
    int v = (threadIdx.x < nb) ? bsum[threadIdx.x] : 0;
    tmp[threadIdx.x] = v;
    __syncthreads();
    for (int ofs = 1; ofs < SCAN_BLOCK; ofs <<= 1) {
        int t = (threadIdx.x >= ofs) ? tmp[threadIdx.x - ofs] : 0;
        __syncthreads();
        tmp[threadIdx.x] += t;
        __syncthreads();
    }
    if (threadIdx.x < nb) bofs[threadIdx.x] = tmp[threadIdx.x] - v;
}

// off[n] = excl[n] + bofs[block]; cur[n] = off[n] (fill cursors)
__global__ void scan3_kernel(const int* __restrict__ excl, const int* __restrict__ bofs,
                             int* __restrict__ off, int* __restrict__ cur, int N) {
    int gid = blockIdx.x * SCAN_BLOCK + threadIdx.x;
    if (gid < N) {
        int o = excl[gid] + bofs[blockIdx.x];
        off[gid] = o;
        cur[gid] = o;
    }
}

__global__ void fill_kernel(const int* __restrict__ src, const int* __restrict__ dst,
                            int* __restrict__ cur, int* __restrict__ eidx, int E) {
    int i = blockIdx.x * blockDim.x + threadIdx.x;
    int stride = gridDim.x * blockDim.x;
    for (; i < E; i += stride) {
        int pos = atomicAdd(&cur[dst[i]], 1);
        eidx[pos] = src[i];
    }
}

// Gather-mean: 16 lanes per node, each lane owns a float4 (16B) of the row.
// Per edge: one fully-coalesced 256B row read (L2/L3-resident x).
__global__ void agg_kernel(const float* __restrict__ xin, const int* __restrict__ eidx,
                           const int* __restrict__ off, const int* __restrict__ cnti,
                           float* __restrict__ mean, int N) {
    int gid = blockIdx.x * blockDim.x + threadIdx.x;
    int node = gid >> 4;
    int lane = gid & 15;
    if (node >= N) return;
    int start = off[node];
    int deg = cnti[node];
    int end = start + deg;
    float4 acc = make_float4(0.f, 0.f, 0.f, 0.f);
    int i = start;
    for (; i + 1 < end; i += 2) {       // unroll-by-2 for ILP (two rows in flight)
        int s0 = eidx[i], s1 = eidx[i + 1];
        float4 v0 = *reinterpret_cast<const float4*>(xin + (size_t)s0 * D + lane * 4);
        float4 v1 = *reinterpret_cast<const float4*>(xin + (size_t)s1 * D + lane * 4);
        acc.x += v0.x + v1.x; acc.y += v0.y + v1.y;
        acc.z += v0.z + v1.z; acc.w += v0.w + v1.w;
    }
    if (i < end) {
        int s0 = eidx[i];
        float4 v0 = *reinterpret_cast<const float4*>(xin + (size_t)s0 * D + lane * 4);
        acc.x += v0.x; acc.y += v0.y; acc.z += v0.z; acc.w += v0.w;
    }
    float r = 1.0f / fmaxf((float)deg, 1.0f);
    acc.x *= r; acc.y *= r; acc.z *= r; acc.w *= r;
    *reinterpret_cast<float4*>(mean + (size_t)node * D + lane * 4) = acc;
}

// out[n][d] = mean[n] . Wl[d,:] + xin[n] . Wr[d,:] + b[d]   (mean pre-divided)
// Block = 256 threads = 4 nodes x 64 dims. W transposed in LDS (+1 pad).
__global__ void layer_kernel(const float* __restrict__ xin,
                             const float* __restrict__ mean,
                             const float* __restrict__ Wl,
                             const float* __restrict__ Wr,
                             const float* __restrict__ b,
                             float* __restrict__ out,
                             int do_relu) {
    __shared__ float wlT[D][D + 1];
    __shared__ float wrT[D][D + 1];
    __shared__ float xrow[4][D];
    __shared__ float mrow[4][D];
    int tid = threadIdx.x;
    for (int j = tid; j < D * D; j += 256) {
        int dd = j >> 6, k = j & 63;
        wlT[k][dd] = Wl[j];
        wrT[k][dd] = Wr[j];
    }
    int local = tid >> 6;
    int d = tid & 63;
    int node = blockIdx.x * 4 + local;   // N divisible by 4, grid exact
    xrow[local][d] = xin[(size_t)node * D + d];
    mrow[local][d] = mean[(size_t)node * D + d];
    __syncthreads();
    float acc = b[d];
#pragma unroll
    for (int k = 0; k < D; ++k) {
        acc = fmaf(mrow[local][k], wlT[k][d], acc);
        acc = fmaf(xrow[local][k], wrT[k][d], acc);
    }
    if (do_relu) acc = fmaxf(acc, 0.0f);
    out[(size_t)node * D + d] = acc;
}

extern "C" void kernel_launch(void* const* d_in, const int* in_sizes, int n_in,
                              void* d_out, int out_size, void* d_ws, size_t ws_size,
                              hipStream_t stream) {
    const float* x   = (const float*)d_in[0];
    const int*   ei  = (const int*)d_in[1];
    const float* Wl1 = (const float*)d_in[2];
    const float* Wr1 = (const float*)d_in[3];
    const float* b1  = (const float*)d_in[4];
    const float* Wl2 = (const float*)d_in[5];
    const float* Wr2 = (const float*)d_in[6];
    const float* b2  = (const float*)d_in[7];

    int N_ = in_sizes[0] / D;   // 50000
    int E_ = in_sizes[1] / 2;   // 800000
    const int* src = ei;
    const int* dst = ei + E_;

    // Workspace layout (16B-aligned boundaries)
    int*   cnti = (int*)d_ws;                       // [N]
    int*   excl = cnti + N_;                        // [N] (block-local exclusive scan)
    int*   cur  = excl + N_;                        // [N] (fill cursors; also reused as off? no)
    int*   off  = cur + N_;                         // [N]
    int*   bsum = off + N_;                         // [256]
    int*   bofs = bsum + 256;                       // [256]
    int*   eidx = bofs + 256;                       // [E]
    float* mean = (float*)(eidx + E_);              // [N, D]
    float* h    = (float*)d_out;                    // layer-1 output lives in d_out (in-place safe)
    float* outp = (float*)d_out;

    int nbScan = (N_ + SCAN_BLOCK - 1) / SCAN_BLOCK;  // 196

    hipMemsetAsync(cnti, 0, (size_t)N_ * sizeof(int), stream);
    counti_kernel<<<2048, 256, 0, stream>>>(dst, cnti, E_);

    // CSR build (shared by both layers)
    scan1_kernel<<<nbScan, SCAN_BLOCK, 0, stream>>>(cnti, excl, bsum, N_);
    scan2_kernel<<<1, SCAN_BLOCK, 0, stream>>>(bsum, bofs, nbScan);
    scan3_kernel<<<nbScan, SCAN_BLOCK, 0, stream>>>(excl, bofs, off, cur, N_);
    fill_kernel<<<2048, 256, 0, stream>>>(src, dst, cur, eidx, E_);

    // Layer 1: mean = gather-mean(x); h = relu(mean@Wl1^T + x@Wr1^T + b1)
    int aggBlocks = (N_ * 16 + 255) / 256;   // 16 lanes/node
    agg_kernel<<<aggBlocks, 256, 0, stream>>>(x, eidx, off, cnti, mean, N_);
    layer_kernel<<<N_ / 4, 256, 0, stream>>>(x, mean, Wl1, Wr1, b1, h, 1);

    // Layer 2: mean2 = gather-mean(h); out = mean2@Wl2^T + h@Wr2^T + b2
    agg_kernel<<<aggBlocks, 256, 0, stream>>>(h, eidx, off, cnti, mean, N_);
    layer_kernel<<<N_ / 4, 256, 0, stream>>>(h, mean, Wl2, Wr2, b2, outp, 0);
}